// Round 5
// baseline (772.553 us; speedup 1.0000x reference)
//
#include <hip/hip_runtime.h>
#include <math.h>

// Problem constants (B=8, H=W=128, C=128, R=4 -> 81 cost channels)
#define BATCH 8
#define HH 128
#define WW 128
#define CC 128
#define RR 4
#define DDIM 9
#define NS 81
#define NSP 96          // cost channels padded to 96 (zero-filled 81..95)
#define HWPIX (HH*WW)
#define DSLAB 1032      // dsh slab stride in shorts (1024 + 8: kills 4-way write conflicts)

typedef short  short8  __attribute__((ext_vector_type(8)));
typedef float  f32x4   __attribute__((ext_vector_type(4)));

__device__ __forceinline__ short bf16h(float f){
    unsigned u = __float_as_uint(f);
    u += 0x7fffu + ((u >> 16) & 1u);
    return (short)(u >> 16);
}
__device__ __forceinline__ float bf16f(short s){
    return __uint_as_float(((unsigned)(unsigned short)s) << 16);
}
__device__ __forceinline__ float mish_f(float x){
    float xc = fminf(x, 30.f);
    float t = expf(xc);
    float u = t*t + 2.f*t;
    return x * (u / (u + 2.f));
}

// async global->LDS DMA, 16 B/lane.  LDS dest = first-active-lane base +
// lane*16 => prefix-only masking, OOB lanes read a zero-scratch global addr.
__device__ __forceinline__ void gld16(float* lds, const float* g){
    __builtin_amdgcn_global_load_lds(
        (const __attribute__((address_space(1))) unsigned int*)g,
        (__attribute__((address_space(3))) unsigned int*)lds, 16, 0, 0);
}

// LDS-only barrier: orders ds_write/ds_read without draining vmcnt.
__device__ __forceinline__ void lds_barrier(){
    __asm volatile("s_waitcnt lgkmcnt(0)\n\ts_barrier" ::: "memory");
}

__global__ void zero_k(float* p, int n){
    int i = blockIdx.x*256 + threadIdx.x;
    if(i < n) p[i] = 0.f;
}

// convert 8 fp32 -> hi/lo bf16 short8 pair
__device__ __forceinline__ void cvt8(const float4& a, const float4& b,
                                     short8& h, short8& l){
    float v0=a.x,v1=a.y,v2=a.z,v3=a.w,v4=b.x,v5=b.y,v6=b.z,v7=b.w;
    short h0=bf16h(v0),h1=bf16h(v1),h2=bf16h(v2),h3=bf16h(v3);
    short h4=bf16h(v4),h5=bf16h(v5),h6=bf16h(v6),h7=bf16h(v7);
    h[0]=h0;h[1]=h1;h[2]=h2;h[3]=h3;h[4]=h4;h[5]=h5;h[6]=h6;h[7]=h7;
    l[0]=bf16h(v0-bf16f(h0)); l[1]=bf16h(v1-bf16f(h1));
    l[2]=bf16h(v2-bf16f(h2)); l[3]=bf16h(v3-bf16f(h3));
    l[4]=bf16h(v4-bf16f(h4)); l[5]=bf16h(v5-bf16f(h5));
    l[6]=bf16h(v6-bf16f(h6)); l[7]=bf16h(v7-bf16f(h7));
}

// ---------------------------------------------------------------------------
// Cost volume as banded GEMM on matrix cores.
// cost(tx,i,j) at row y = band of A.B^T: A = prv[y][x0..x0+15][:] (16x128),
// B = nxt[y+i-4][x0-4..x0+19][:] (24x128).  Two 16x16 n-tiles (u=0..15,
// u=8..23) cover the 9-diagonal band.  Split-bf16 4-term MFMA (hh+lh+hl+ll)
// for ~fp32 accuracy (same scheme as sep_mfma's pointwise).
// Block: 16x16 px, 512 thr / 8 waves; wave = 2 y-rows x 9 i.  nxt staged
// per-32ch-chunk in LDS as frag-ready hi/lo short slabs [r24][q4][c24][8]
// (72 KB -> 2 blocks/CU).  kc loop: reg-staged global loads issued before
// compute (T14), single LDS buffer, barrier-separated.
// ---------------------------------------------------------------------------
__global__ __launch_bounds__(512,4) void cost_mfma(
    const float* __restrict__ prv, const float* __restrict__ nxt,
    float* __restrict__ cost)
{
    __shared__ short bhs[24*4*24*8];    // [r][ch-octet][col][8ch] hi
    __shared__ short bls[24*4*24*8];    // lo
    const int tid  = threadIdx.x;
    const int lane = tid & 63, wv = tid >> 6;      // wv 0..7
    const int l15  = lane & 15, quad = lane >> 4;
    const int x0 = blockIdx.x*16, y0 = blockIdx.y*16, b = blockIdx.z;
    const int Y = wv*2;                             // wave's 2 tile rows

    const float* prvb = prv + (((size_t)b*HH + y0)*WW + x0)*CC;
    const float* nxb  = nxt + (size_t)b*HH*WW*CC;

    f32x4 acc[2][9][2];
#pragma unroll
    for(int yy=0;yy<2;yy++)
#pragma unroll
        for(int i=0;i<9;i++){
            acc[yy][i][0] = (f32x4){0.f,0.f,0.f,0.f};
            acc[yy][i][1] = (f32x4){0.f,0.f,0.f,0.f};
        }

    // zero pad channels 81..95 (disjoint from job channels 0..80 -> no race)
    if(tid < 256){
        float* zp = cost + (((size_t)b*HH + y0 + (tid>>4))*WW + x0 + (tid&15))*NSP;
        zp[81]=0.f; zp[82]=0.f; zp[83]=0.f;
        float4 z4 = make_float4(0.f,0.f,0.f,0.f);
        *(float4*)(zp+84)=z4; *(float4*)(zp+88)=z4; *(float4*)(zp+92)=z4;
    }

    float4 sreg[9];
    auto sload = [&](int kc){
#pragma unroll
        for(int s=0;s<9;s++){
            int e = s*512 + tid;                    // 0..4607, bijective
            int px = e >> 3, q = e & 7;             // px 0..575, ch-quartet
            int r = px/24, c = px - r*24;
            int hy = y0 - 4 + r, hx = x0 - 4 + c;
            bool ok = hy>=0 && hy<HH && hx>=0 && hx<WW;
            sreg[s] = ok ? *(const float4*)(nxb + ((size_t)hy*WW + hx)*CC + kc*32 + q*4)
                         : make_float4(0.f,0.f,0.f,0.f);
        }
    };
    sload(0);

    for(int kc=0; kc<4; kc++){
        __syncthreads();                 // readers of previous chunk done
        // ---- write staged regs -> frag-ready hi/lo slabs ----
#pragma unroll
        for(int s=0;s<9;s++){
            int e = s*512 + tid;
            int px = e >> 3, q = e & 7;
            int r = px/24, c = px - r*24;
            int base = ((r*4 + (q>>1))*24 + c)*8 + (q&1)*4;
            float4 v = sreg[s];
            short h0=bf16h(v.x), h1=bf16h(v.y), h2=bf16h(v.z), h3=bf16h(v.w);
            *(short4*)&bhs[base] = make_short4(h0,h1,h2,h3);
            *(short4*)&bls[base] = make_short4(bf16h(v.x-bf16f(h0)),
                                               bf16h(v.y-bf16f(h1)),
                                               bf16h(v.z-bf16f(h2)),
                                               bf16h(v.w-bf16f(h3)));
        }
        if(kc < 3) sload(kc+1);          // prefetch next chunk (T14)
        // ---- A-frags: prv rows, direct global + convert ----
        short8 Ah[2], Al[2];
#pragma unroll
        for(int yy=0; yy<2; yy++){
            const float* ap = prvb + ((size_t)(Y+yy)*WW + l15)*CC + kc*32 + quad*8;
            float4 f0v = *(const float4*)ap;
            float4 f1v = *(const float4*)(ap+4);
            cvt8(f0v, f1v, Ah[yy], Al[yy]);
        }
        lds_barrier();                   // slab writes visible
        // ---- banded MFMA: rows r = Y..Y+9, jobs (yy, i=rr-yy) ----
#pragma unroll
        for(int rr=0; rr<10; rr++){
            int r  = Y + rr;
            int rb = (r*4 + quad)*24*8;
            short8 Bh0 = *(const short8*)&bhs[rb + l15*8];
            short8 Bl0 = *(const short8*)&bls[rb + l15*8];
            short8 Bh1 = *(const short8*)&bhs[rb + (8+l15)*8];
            short8 Bl1 = *(const short8*)&bls[rb + (8+l15)*8];
#pragma unroll
            for(int yy=0; yy<2; yy++){
                int i = rr - yy;
                if(i >= 0 && i <= 8){
                    f32x4 c0 = acc[yy][i][0];
                    c0 = __builtin_amdgcn_mfma_f32_16x16x32_bf16(Ah[yy],Bh0,c0,0,0,0);
                    c0 = __builtin_amdgcn_mfma_f32_16x16x32_bf16(Al[yy],Bh0,c0,0,0,0);
                    c0 = __builtin_amdgcn_mfma_f32_16x16x32_bf16(Ah[yy],Bl0,c0,0,0,0);
                    c0 = __builtin_amdgcn_mfma_f32_16x16x32_bf16(Al[yy],Bl0,c0,0,0,0);
                    acc[yy][i][0] = c0;
                    f32x4 c1 = acc[yy][i][1];
                    c1 = __builtin_amdgcn_mfma_f32_16x16x32_bf16(Ah[yy],Bh1,c1,0,0,0);
                    c1 = __builtin_amdgcn_mfma_f32_16x16x32_bf16(Al[yy],Bh1,c1,0,0,0);
                    c1 = __builtin_amdgcn_mfma_f32_16x16x32_bf16(Ah[yy],Bl1,c1,0,0,0);
                    c1 = __builtin_amdgcn_mfma_f32_16x16x32_bf16(Al[yy],Bl1,c1,0,0,0);
                    acc[yy][i][1] = c1;
                }
            }
        }
    }
    // ---- epilogue: extract band, scale, scatter-store ----
    // D layout: row m = quad*4+reg, col n = l15.  nt0: u=n (j=n-m);
    // nt1: u=8+n (j=8+n-m).  Partition by u<16 / u>=16: no double-writes.
    const float sc = 1.f/128.f;
#pragma unroll
    for(int yy=0; yy<2; yy++){
        float* orow = cost + (((size_t)b*HH + (y0+Y+yy))*WW + x0)*NSP;
#pragma unroll
        for(int i=0;i<9;i++){
#pragma unroll
            for(int rg=0; rg<4; rg++){
                int m  = quad*4 + rg;
                int j0 = l15 - m;
                if(j0 >= 0 && j0 <= 8)
                    orow[(size_t)m*NSP + i*9 + j0] = acc[yy][i][0][rg]*sc;
                int j1 = 8 + l15 - m;
                if(l15 >= 8 && j1 <= 8)
                    orow[(size_t)m*NSP + i*9 + j1] = acc[yy][i][1][rg]*sc;
            }
        }
    }
}

// ---------------------------------------------------------------------------
// Pointwise weight prep (hi/lo bf16 B-fragment slabs), remap for padded concat.
// ---------------------------------------------------------------------------
__global__ void prep_pw(const float* __restrict__ src, short* __restrict__ dh,
                        short* __restrict__ dl, int K, int N, int NP, int total,
                        int remap)
{
    int idx = blockIdx.x*256 + threadIdx.x;
    if(idx >= total) return;
    int j  = idx & 7;
    int n  = (idx>>3) % NP;
    int k8 = (idx>>3) / NP;
    int k  = k8*8 + j;
    if(remap) k = (k < 81) ? k : ((k < 96) ? -1 : k - 15);
    float v = (k>=0 && k<K && n<N) ? src[(size_t)k*N + n] : 0.f;
    short h = bf16h(v);
    dh[idx] = h;
    dl[idx] = bf16h(v - bf16f(h));
}

// Depthwise weight prep: [9][K0] slab, remapped/zero-padded.
__global__ void prep_dw(const float* __restrict__ src, float* __restrict__ dst,
                        int K, int K0, int remap, int total)
{
    int idx = blockIdx.x*256 + threadIdx.x;
    if(idx >= total) return;
    int k = idx / K0, c = idx - k*K0;
    int cr = c;
    if(remap) cr = (c < 81) ? c : ((c < 96) ? -1 : c - 15);
    dst[idx] = (cr>=0 && cr<K) ? src[k*K + cr] : 0.f;
}

// ---------------------------------------------------------------------------
// Fused depthwise-3x3 (fp32 VALU) + pointwise-1x1 (split-bf16 MFMA, fp32 acc).
// Tile 16x8 px, 4 waves 2(m)x2(n).  K-chunks of 32, double-buffered DMA
// staging; chunk k+1's DMA issued after chunk k's opening barrier; lgkm-only
// mid barrier keeps the prefetch in flight through the MFMA phase.
// Depthwise: one thread = 4 consecutive px x 4 ch (sliding 6-col window).
// dsh slab stride DSLAB=1032 shorts kills the 4-way write conflicts.
// ---------------------------------------------------------------------------
template<int CINR,int K0,int COUT,int NP,bool BIAS,bool ACT,bool CONCAT>
__global__ __launch_bounds__(256,2) void sep_mfma(
    const float* __restrict__ xin, const float* __restrict__ cost,
    const float* __restrict__ prv, const float* __restrict__ nxt,
    const float* __restrict__ dwp, const short* __restrict__ wh,
    const short* __restrict__ wl, const float* __restrict__ bias,
    const float* __restrict__ zb, float* __restrict__ out)
{
    constexpr int TN = NP/32;           // n-tiles per wave (16 couts each)
    __shared__ float xs[2][180*36];     // halo 10(y) x 18(x), stride 36
    __shared__ short dshh[4*DSLAB];     // [k8][px][j]  hi
    __shared__ short dshl[4*DSLAB];     // [k8][px][j]  lo
    __shared__ float dwls[2][9*32];

    const int tid = threadIdx.x;
    const int x0 = blockIdx.x*16, y0 = blockIdx.y*8, b = blockIdx.z;
    const int lane = tid & 63;
    const int wv   = tid >> 6;
    const int wm   = wv >> 1, wn = wv & 1;
    const int l15  = lane & 15, quad = lane >> 4;

    f32x4 acc[4][TN];
#pragma unroll
    for(int i=0;i<4;i++)
#pragma unroll
        for(int nt=0;nt<TN;nt++) acc[i][nt] = (f32x4){0.f,0.f,0.f,0.f};

    auto stage = [&](int c0, int pb){
        if(tid < 72)
            gld16(&dwls[pb][(tid>>3)*32 + (tid&7)*4],
                  dwp + (tid>>3)*K0 + c0 + (tid&7)*4);
        const float* src; int str, coff;
        if(CONCAT){
            if(c0 < 96)      { src = cost; str = NSP; coff = c0; }
            else if(c0 < 224){ src = prv;  str = 128; coff = c0-96; }
            else             { src = nxt;  str = 128; coff = c0-224; }
        } else { src = xin; str = CINR; coff = c0; }
        const float* sb = src + (size_t)b*HH*WW*str + coff;
        float* xp = &xs[pb][0];
#pragma unroll
        for(int it=0;it<7;it++){
            int e = it*256 + tid;
            if(e < 1620){                               // prefix mask only
                int hp = e/9, q = e - hp*9;
                int hy = y0-1 + hp/18, hx = x0-1 + hp%18;
                bool ok = (q < 8) && hy>=0 && hy<HH && hx>=0 && hx<WW;
                const float* gp = ok ? (sb + ((size_t)hy*WW + hx)*str + q*4)
                                     : zb;
                gld16(xp + hp*36 + q*4, gp);
            }
        }
    };

    // depthwise work identity: 4 consecutive px (same row), 4 channels
    const int c4  = tid & 7;           // channel quartet 0..7
    const int pxg = tid >> 3;          // pixel group 0..31
    const int dpy = pxg >> 2;          // tile row 0..7
    const int dxb = (pxg & 3) * 4;     // tile col base 0,4,8,12

    stage(0, 0);
    int pb = 0;
    for(int c0=0;c0<K0;c0+=32){
        __syncthreads();   // drains this chunk's DMA (issued last iteration)
        // ---- B fragments for this chunk (issued before prefetch DMA) ----
        const int k8 = (c0>>3) + quad;
        short8 Bh[TN], Bl[TN];
#pragma unroll
        for(int nt=0;nt<TN;nt++){
            int n = wn*(NP/2) + nt*16 + l15;
            size_t off = ((size_t)k8*NP + n)*8;
            Bh[nt] = *(const short8*)(wh + off);
            Bl[nt] = *(const short8*)(wl + off);
        }
        // ---- prefetch next chunk into the other buffer ----
        if(c0+32 < K0) stage(c0+32, pb^1);
        // ---- depthwise 3x3: 4 px x 4 ch per thread, sliding 6-col window ----
        const float* xp = &xs[pb][0];
        const float* dwc = &dwls[pb][0];
        {
            float4 o[4];
#pragma unroll
            for(int dx=0;dx<4;dx++) o[dx] = make_float4(0.f,0.f,0.f,0.f);
#pragma unroll
            for(int kh=0;kh<3;kh++){
                float4 xw[6];
#pragma unroll
                for(int t=0;t<6;t++)
                    xw[t] = *(const float4*)&xp[((dpy+kh)*18 + dxb + t)*36 + c4*4];
#pragma unroll
                for(int kw=0;kw<3;kw++){
                    float4 w4 = *(const float4*)&dwc[(kh*3+kw)*32 + c4*4];
#pragma unroll
                    for(int dx=0;dx<4;dx++){
                        float4 xv = xw[kw+dx];
                        o[dx].x = fmaf(xv.x,w4.x,o[dx].x);
                        o[dx].y = fmaf(xv.y,w4.y,o[dx].y);
                        o[dx].z = fmaf(xv.z,w4.z,o[dx].z);
                        o[dx].w = fmaf(xv.w,w4.w,o[dx].w);
                    }
                }
            }
            const int wbase = (c4>>1)*DSLAB + (pxg*4)*8 + (c4&1)*4;
#pragma unroll
            for(int dx=0;dx<4;dx++){
                float4 s = o[dx];
                short h0=bf16h(s.x), h1=bf16h(s.y), h2=bf16h(s.z), h3=bf16h(s.w);
                short l0=bf16h(s.x-bf16f(h0)), l1=bf16h(s.y-bf16f(h1));
                short l2=bf16h(s.z-bf16f(h2)), l3=bf16h(s.w-bf16f(h3));
                *(short4*)&dshh[wbase + dx*8] = make_short4(h0,h1,h2,h3);
                *(short4*)&dshl[wbase + dx*8] = make_short4(l0,l1,l2,l3);
            }
        }
        lds_barrier();     // orders dsh writes/reads; DMA keeps flying
        // ---- MFMA: A from LDS, B from registers ----
#pragma unroll
        for(int i=0;i<4;i++){
            int ab = quad*DSLAB + (wm*64 + i*16 + l15)*8;
            short8 Ah = *(const short8*)&dshh[ab];
            short8 Al = *(const short8*)&dshl[ab];
#pragma unroll
            for(int nt=0;nt<TN;nt++){
                f32x4 c = acc[i][nt];
                c = __builtin_amdgcn_mfma_f32_16x16x32_bf16(Ah,Bh[nt],c,0,0,0);
                c = __builtin_amdgcn_mfma_f32_16x16x32_bf16(Al,Bh[nt],c,0,0,0);
                c = __builtin_amdgcn_mfma_f32_16x16x32_bf16(Ah,Bl[nt],c,0,0,0);
                acc[i][nt] = c;
            }
        }
        lds_barrier();     // dsh reads done before next chunk's dw writes
        pb ^= 1;
    }
    // ---- epilogue: bias + mish + store ----
#pragma unroll
    for(int i=0;i<4;i++){
        int pxb = wm*64 + i*16 + quad*4;
#pragma unroll
        for(int nt=0;nt<TN;nt++){
            int cout = wn*(NP/2) + nt*16 + l15;
            if(cout < COUT){
                float bv = BIAS ? bias[cout] : 0.f;
#pragma unroll
                for(int r=0;r<4;r++){
                    int p = pxb + r;
                    int y = y0 + (p>>4), x = x0 + (p&15);
                    float v = acc[i][nt][r] + bv;
                    if(ACT) v = mish_f(v);
                    out[(((size_t)b*HH + y)*WW + x)*COUT + cout] = v;
                }
            }
        }
    }
}

// ---------------------------------------------------------------------------
extern "C" void kernel_launch(void* const* d_in, const int* in_sizes, int n_in,
                              void* d_out, int out_size, void* d_ws, size_t ws_size,
                              hipStream_t stream)
{
    (void)in_sizes; (void)n_in; (void)out_size;
    const float* prv = (const float*)d_in[0];
    const float* nxt = (const float*)d_in[1];
    const float* dws[6] = {(const float*)d_in[2],(const float*)d_in[5],(const float*)d_in[8],
                           (const float*)d_in[11],(const float*)d_in[14],(const float*)d_in[17]};
    const float* pws[6] = {(const float*)d_in[3],(const float*)d_in[6],(const float*)d_in[9],
                           (const float*)d_in[12],(const float*)d_in[15],(const float*)d_in[18]};
    const float* b0  = (const float*)d_in[4];
    const float* b1  = (const float*)d_in[7];
    const float* b2  = (const float*)d_in[10];
    const float* b3  = (const float*)d_in[13];
    const float* b4  = (const float*)d_in[16];

    // ---- weight slabs: pw hi/lo bf16 + dw fp32 [9][K0] + zero scratch ----
    const int   Ks[6]   = {337,128,128, 96, 64, 32};
    const int   K0s[6]  = {352,128,128, 96, 64, 32};
    const int   Ns[6]   = {128,128, 96, 64, 32,  2};
    const int   NPs[6]  = {128,128, 96, 64, 32, 32};
    const int   rmp[6]  = {  1,  0,  0,  0,  0,  0};
    size_t offs[6]; size_t E = 0;
    for(int i=0;i<6;i++){ offs[i] = E; E += (size_t)K0s[i]*NPs[i]; }
    size_t dwoffs[6]; size_t Edw = 0;
    for(int i=0;i<6;i++){ dwoffs[i] = Edw; Edw += (size_t)9*K0s[i]; }

    short* Whs = (short*)d_ws;
    short* Wls = Whs + E;
    float* Dwp = (float*)((char*)d_ws + ((E*2*sizeof(short) + 255) & ~(size_t)255));
    float* Zb  = Dwp + Edw;                    // 64-float zero scratch
    size_t wbytes = (((char*)(Zb + 64) - (char*)d_ws) + 255) & ~(size_t)255;

    zero_k<<<1,64,0,stream>>>(Zb, 64);
    for(int i=0;i<6;i++){
        int total = K0s[i]*NPs[i];
        prep_pw<<<(total+255)/256,256,0,stream>>>(pws[i], Whs+offs[i], Wls+offs[i],
                                                  Ks[i], Ns[i], NPs[i], total, rmp[i]);
        int tdw = 9*K0s[i];
        prep_dw<<<(tdw+255)/256,256,0,stream>>>(dws[i], Dwp+dwoffs[i],
                                                Ks[i], K0s[i], rmp[i], tdw);
    }

    // ---- activation buffers, batch-chunked ----
    const size_t per_batch_floats = (size_t)HWPIX * (NSP + 128 + 128);
    size_t avail = (ws_size > wbytes) ? (ws_size - wbytes) : 0;
    int NB = (int)(avail / (per_batch_floats * sizeof(float)));
    if(NB > BATCH) NB = BATCH;
    if(NB < 1)     NB = 1;
    while(BATCH % NB) NB--;

    float* fbase = (float*)((char*)d_ws + wbytes);
    float* costb = fbase;
    float* bufA  = costb + (size_t)NB*HWPIX*NSP;
    float* bufB  = bufA  + (size_t)NB*HWPIX*128;

    for(int bb=0; bb<BATCH; bb+=NB){
        const float* prv_o = prv + (size_t)bb*HWPIX*CC;
        const float* nxt_o = nxt + (size_t)bb*HWPIX*CC;
        float*       out_o = (float*)d_out + (size_t)bb*HWPIX*2;
        dim3 gc(WW/16, HH/16, NB);
        dim3 gs(WW/16, HH/8,  NB);

        cost_mfma<<<gc,512,0,stream>>>(prv_o, nxt_o, costb);
        sep_mfma<337,352,128,128,true ,true ,true ><<<gs,256,0,stream>>>(nullptr, costb, prv_o, nxt_o, Dwp+dwoffs[0], Whs+offs[0], Wls+offs[0], b0, Zb, bufA);
        sep_mfma<128,128,128,128,true ,true ,false><<<gs,256,0,stream>>>(bufA, nullptr,nullptr,nullptr, Dwp+dwoffs[1], Whs+offs[1], Wls+offs[1], b1, Zb, bufB);
        sep_mfma<128,128, 96, 96,true ,true ,false><<<gs,256,0,stream>>>(bufB, nullptr,nullptr,nullptr, Dwp+dwoffs[2], Whs+offs[2], Wls+offs[2], b2, Zb, bufA);
        sep_mfma< 96, 96, 64, 64,true ,true ,false><<<gs,256,0,stream>>>(bufA, nullptr,nullptr,nullptr, Dwp+dwoffs[3], Whs+offs[3], Wls+offs[3], b3, Zb, bufB);
        sep_mfma< 64, 64, 32, 32,true ,true ,false><<<gs,256,0,stream>>>(bufB, nullptr,nullptr,nullptr, Dwp+dwoffs[4], Whs+offs[4], Wls+offs[4], b4, Zb, bufA);
        sep_mfma< 32, 32,  2, 32,false,false,false><<<gs,256,0,stream>>>(bufA, nullptr,nullptr,nullptr, Dwp+dwoffs[5], Whs+offs[5], Wls+offs[5], nullptr, Zb, out_o);
    }
}

// Round 6
// 760.898 us; speedup vs baseline: 1.0153x; 1.0153x over previous
//
#include <hip/hip_runtime.h>
#include <math.h>

// Problem constants (B=8, H=W=128, C=128, R=4 -> 81 cost channels)
#define BATCH 8
#define HH 128
#define WW 128
#define CC 128
#define RR 4
#define DDIM 9
#define NS 81
#define NSP 96          // cost channels padded to 96 (zero-filled 81..95)
#define HWPIX (HH*WW)
#define DSLAB 1032      // dsh slab stride in shorts (1024 + 8: kills 4-way write conflicts)

typedef short  short8  __attribute__((ext_vector_type(8)));
typedef float  f32x4   __attribute__((ext_vector_type(4)));

__device__ __forceinline__ short bf16h(float f){
    unsigned u = __float_as_uint(f);
    u += 0x7fffu + ((u >> 16) & 1u);
    return (short)(u >> 16);
}
__device__ __forceinline__ float bf16f(short s){
    return __uint_as_float(((unsigned)(unsigned short)s) << 16);
}
__device__ __forceinline__ float mish_f(float x){
    float xc = fminf(x, 30.f);
    float t = expf(xc);
    float u = t*t + 2.f*t;
    return x * (u / (u + 2.f));
}

// async global->LDS DMA, 16 B/lane.  LDS dest = first-active-lane base +
// lane*16 => prefix-only masking, OOB lanes read a zero-scratch global addr.
__device__ __forceinline__ void gld16(float* lds, const float* g){
    __builtin_amdgcn_global_load_lds(
        (const __attribute__((address_space(1))) unsigned int*)g,
        (__attribute__((address_space(3))) unsigned int*)lds, 16, 0, 0);
}

// LDS-only barrier: orders ds_write/ds_read without draining vmcnt.
__device__ __forceinline__ void lds_barrier(){
    __asm volatile("s_waitcnt lgkmcnt(0)\n\ts_barrier" ::: "memory");
}

__global__ void zero_k(float* p, int n){
    int i = blockIdx.x*256 + threadIdx.x;
    if(i < n) p[i] = 0.f;
}

// convert 8 fp32 -> hi/lo bf16 short8 pair
__device__ __forceinline__ void cvt8(const float4& a, const float4& b,
                                     short8& h, short8& l){
    float v0=a.x,v1=a.y,v2=a.z,v3=a.w,v4=b.x,v5=b.y,v6=b.z,v7=b.w;
    short h0=bf16h(v0),h1=bf16h(v1),h2=bf16h(v2),h3=bf16h(v3);
    short h4=bf16h(v4),h5=bf16h(v5),h6=bf16h(v6),h7=bf16h(v7);
    h[0]=h0;h[1]=h1;h[2]=h2;h[3]=h3;h[4]=h4;h[5]=h5;h[6]=h6;h[7]=h7;
    l[0]=bf16h(v0-bf16f(h0)); l[1]=bf16h(v1-bf16f(h1));
    l[2]=bf16h(v2-bf16f(h2)); l[3]=bf16h(v3-bf16f(h3));
    l[4]=bf16h(v4-bf16f(h4)); l[5]=bf16h(v5-bf16f(h5));
    l[6]=bf16h(v6-bf16f(h6)); l[7]=bf16h(v7-bf16f(h7));
}

// ---------------------------------------------------------------------------
// Cost volume as banded GEMM on matrix cores.
// cost(tx,i,j) at row y = band of A.B^T: A = prv[y][x0..x0+15][:] (16x128),
// B = nxt[y+i-4][x0-4..x0+19][:] (24x128).  Two 16x16 n-tiles cover the
// 9-diagonal band.  Split-bf16 4-term MFMA for ~fp32 accuracy.
// Block 16x16 px, 512 thr / 8 waves; wave = 2 y-rows x 9 i.  nxt staged
// per-32ch-chunk in LDS as frag-ready hi/lo short slabs.
// Epilogue: band values scattered into LDS (reusing the slab buffer as a
// 128px x 96ch staging area, 2 passes of 8 rows), pad channels zeroed in
// LDS, then streamed out as contiguous float4 stores.  The r5 version's
// scalar scatter-stores caused 12x write amplification (626 MB/dispatch) +
// RMW-allocate fetch amplification -- the entire 313 us was HBM.
// ---------------------------------------------------------------------------
__global__ __launch_bounds__(512,4) void cost_mfma(
    const float* __restrict__ prv, const float* __restrict__ nxt,
    float* __restrict__ cost)
{
    __shared__ char smem[73728];
    short* bhs = (short*)smem;              // [r][ch-octet][col][8ch] hi (36864 B)
    short* bls = (short*)(smem + 36864);    // lo (36864 B)
    const int tid  = threadIdx.x;
    const int lane = tid & 63, wv = tid >> 6;      // wv 0..7
    const int l15  = lane & 15, quad = lane >> 4;
    const int x0 = blockIdx.x*16, y0 = blockIdx.y*16, b = blockIdx.z;
    const int Y = wv*2;                             // wave's 2 tile rows

    const float* prvb = prv + (((size_t)b*HH + y0)*WW + x0)*CC;
    const float* nxb  = nxt + (size_t)b*HH*WW*CC;

    f32x4 acc[2][9][2];
#pragma unroll
    for(int yy=0;yy<2;yy++)
#pragma unroll
        for(int i=0;i<9;i++){
            acc[yy][i][0] = (f32x4){0.f,0.f,0.f,0.f};
            acc[yy][i][1] = (f32x4){0.f,0.f,0.f,0.f};
        }

    float4 sreg[9];
    auto sload = [&](int kc){
#pragma unroll
        for(int s=0;s<9;s++){
            int e = s*512 + tid;                    // 0..4607, bijective
            int px = e >> 3, q = e & 7;             // px 0..575, ch-quartet
            int r = px/24, c = px - r*24;
            int hy = y0 - 4 + r, hx = x0 - 4 + c;
            bool ok = hy>=0 && hy<HH && hx>=0 && hx<WW;
            sreg[s] = ok ? *(const float4*)(nxb + ((size_t)hy*WW + hx)*CC + kc*32 + q*4)
                         : make_float4(0.f,0.f,0.f,0.f);
        }
    };
    sload(0);

    for(int kc=0; kc<4; kc++){
        __syncthreads();                 // readers of previous chunk done
        // ---- write staged regs -> frag-ready hi/lo slabs ----
#pragma unroll
        for(int s=0;s<9;s++){
            int e = s*512 + tid;
            int px = e >> 3, q = e & 7;
            int r = px/24, c = px - r*24;
            int base = ((r*4 + (q>>1))*24 + c)*8 + (q&1)*4;
            float4 v = sreg[s];
            short h0=bf16h(v.x), h1=bf16h(v.y), h2=bf16h(v.z), h3=bf16h(v.w);
            *(short4*)&bhs[base] = make_short4(h0,h1,h2,h3);
            *(short4*)&bls[base] = make_short4(bf16h(v.x-bf16f(h0)),
                                               bf16h(v.y-bf16f(h1)),
                                               bf16h(v.z-bf16f(h2)),
                                               bf16h(v.w-bf16f(h3)));
        }
        if(kc < 3) sload(kc+1);          // prefetch next chunk (T14)
        // ---- A-frags: prv rows, direct global + convert ----
        short8 Ah[2], Al[2];
#pragma unroll
        for(int yy=0; yy<2; yy++){
            const float* ap = prvb + ((size_t)(Y+yy)*WW + l15)*CC + kc*32 + quad*8;
            float4 f0v = *(const float4*)ap;
            float4 f1v = *(const float4*)(ap+4);
            cvt8(f0v, f1v, Ah[yy], Al[yy]);
        }
        lds_barrier();                   // slab writes visible
        // ---- banded MFMA: rows r = Y..Y+9, jobs (yy, i=rr-yy) ----
#pragma unroll
        for(int rr=0; rr<10; rr++){
            int r  = Y + rr;
            int rb = (r*4 + quad)*24*8;
            short8 Bh0 = *(const short8*)&bhs[rb + l15*8];
            short8 Bl0 = *(const short8*)&bls[rb + l15*8];
            short8 Bh1 = *(const short8*)&bhs[rb + (8+l15)*8];
            short8 Bl1 = *(const short8*)&bls[rb + (8+l15)*8];
#pragma unroll
            for(int yy=0; yy<2; yy++){
                int i = rr - yy;
                if(i >= 0 && i <= 8){
                    f32x4 c0 = acc[yy][i][0];
                    c0 = __builtin_amdgcn_mfma_f32_16x16x32_bf16(Ah[yy],Bh0,c0,0,0,0);
                    c0 = __builtin_amdgcn_mfma_f32_16x16x32_bf16(Al[yy],Bh0,c0,0,0,0);
                    c0 = __builtin_amdgcn_mfma_f32_16x16x32_bf16(Ah[yy],Bl0,c0,0,0,0);
                    c0 = __builtin_amdgcn_mfma_f32_16x16x32_bf16(Al[yy],Bl0,c0,0,0,0);
                    acc[yy][i][0] = c0;
                    f32x4 c1 = acc[yy][i][1];
                    c1 = __builtin_amdgcn_mfma_f32_16x16x32_bf16(Ah[yy],Bh1,c1,0,0,0);
                    c1 = __builtin_amdgcn_mfma_f32_16x16x32_bf16(Al[yy],Bh1,c1,0,0,0);
                    c1 = __builtin_amdgcn_mfma_f32_16x16x32_bf16(Ah[yy],Bl1,c1,0,0,0);
                    c1 = __builtin_amdgcn_mfma_f32_16x16x32_bf16(Al[yy],Bl1,c1,0,0,0);
                    acc[yy][i][1] = c1;
                }
            }
        }
    }
    // ---- epilogue: scatter band -> LDS staging -> coalesced float4 stores.
    // D layout: row m = quad*4+reg, col n = l15.  nt0: j=n-m; nt1: j=8+n-m.
    // Partition by u<16 / u>=16: each (m, j) has exactly one writer, all 81
    // channels covered.  2 passes x 8 rows (49152 B staging <= 73728 B smem).
    const float sc = 1.f/128.f;
    float* obuf = (float*)smem;          // [128 px][96 ch]
    const int grp = wv >> 2;             // wave row-group == pass index
#pragma unroll
    for(int p=0; p<2; p++){
        lds_barrier();                   // prior smem readers done
        if(grp == p){                    // wave-uniform branch, no barrier inside
#pragma unroll
            for(int yy=0; yy<2; yy++){
                int rl = (Y + yy - p*8)*16;        // local px row base
#pragma unroll
                for(int i=0;i<9;i++){
#pragma unroll
                    for(int rg=0; rg<4; rg++){
                        int m  = quad*4 + rg;
                        int j0 = l15 - m;
                        if(j0 >= 0 && j0 <= 8)
                            obuf[(rl + m)*96 + i*9 + j0] = acc[yy][i][0][rg]*sc;
                        int j1 = 8 + l15 - m;
                        if(l15 >= 8 && j1 <= 8)
                            obuf[(rl + m)*96 + i*9 + j1] = acc[yy][i][1][rg]*sc;
                    }
                }
            }
        }
        // zero pad channels 81..95 (disjoint addresses from the scatter)
        for(int e = tid; e < 1920; e += 512){
            int px = e/15, c = e - px*15;
            obuf[px*96 + 81 + c] = 0.f;
        }
        lds_barrier();
        // rows y0+8p..+7: per row 16 px x 96 ch = 1536 floats contiguous
        float* gbase = cost + (((size_t)b*HH + y0 + p*8)*WW + x0)*NSP;
#pragma unroll
        for(int it=0; it<6; it++){
            int e = it*512 + tid;        // 0..3071 float4 slots
            int r = e/384, o = e - r*384;
            float4 v = *(const float4*)&obuf[r*1536 + o*4];
            *(float4*)&gbase[(size_t)r*WW*NSP + o*4] = v;
        }
    }
}

// ---------------------------------------------------------------------------
// Pointwise weight prep (hi/lo bf16 B-fragment slabs), remap for padded concat.
// ---------------------------------------------------------------------------
__global__ void prep_pw(const float* __restrict__ src, short* __restrict__ dh,
                        short* __restrict__ dl, int K, int N, int NP, int total,
                        int remap)
{
    int idx = blockIdx.x*256 + threadIdx.x;
    if(idx >= total) return;
    int j  = idx & 7;
    int n  = (idx>>3) % NP;
    int k8 = (idx>>3) / NP;
    int k  = k8*8 + j;
    if(remap) k = (k < 81) ? k : ((k < 96) ? -1 : k - 15);
    float v = (k>=0 && k<K && n<N) ? src[(size_t)k*N + n] : 0.f;
    short h = bf16h(v);
    dh[idx] = h;
    dl[idx] = bf16h(v - bf16f(h));
}

// Depthwise weight prep: [9][K0] slab, remapped/zero-padded.
__global__ void prep_dw(const float* __restrict__ src, float* __restrict__ dst,
                        int K, int K0, int remap, int total)
{
    int idx = blockIdx.x*256 + threadIdx.x;
    if(idx >= total) return;
    int k = idx / K0, c = idx - k*K0;
    int cr = c;
    if(remap) cr = (c < 81) ? c : ((c < 96) ? -1 : c - 15);
    dst[idx] = (cr>=0 && cr<K) ? src[k*K + cr] : 0.f;
}

// ---------------------------------------------------------------------------
// Fused depthwise-3x3 (fp32 VALU) + pointwise-1x1 (split-bf16 MFMA, fp32 acc).
// Tile 16x8 px, 4 waves 2(m)x2(n).  K-chunks of 32, double-buffered DMA
// staging; chunk k+1's DMA issued after chunk k's opening barrier; lgkm-only
// mid barrier keeps the prefetch in flight through the MFMA phase.
// Depthwise: one thread = 4 consecutive px x 4 ch (sliding 6-col window).
// dsh slab stride DSLAB=1032 shorts kills the 4-way write conflicts.
// ---------------------------------------------------------------------------
template<int CINR,int K0,int COUT,int NP,bool BIAS,bool ACT,bool CONCAT>
__global__ __launch_bounds__(256,2) void sep_mfma(
    const float* __restrict__ xin, const float* __restrict__ cost,
    const float* __restrict__ prv, const float* __restrict__ nxt,
    const float* __restrict__ dwp, const short* __restrict__ wh,
    const short* __restrict__ wl, const float* __restrict__ bias,
    const float* __restrict__ zb, float* __restrict__ out)
{
    constexpr int TN = NP/32;           // n-tiles per wave (16 couts each)
    __shared__ float xs[2][180*36];     // halo 10(y) x 18(x), stride 36
    __shared__ short dshh[4*DSLAB];     // [k8][px][j]  hi
    __shared__ short dshl[4*DSLAB];     // [k8][px][j]  lo
    __shared__ float dwls[2][9*32];

    const int tid = threadIdx.x;
    const int x0 = blockIdx.x*16, y0 = blockIdx.y*8, b = blockIdx.z;
    const int lane = tid & 63;
    const int wv   = tid >> 6;
    const int wm   = wv >> 1, wn = wv & 1;
    const int l15  = lane & 15, quad = lane >> 4;

    f32x4 acc[4][TN];
#pragma unroll
    for(int i=0;i<4;i++)
#pragma unroll
        for(int nt=0;nt<TN;nt++) acc[i][nt] = (f32x4){0.f,0.f,0.f,0.f};

    auto stage = [&](int c0, int pb){
        if(tid < 72)
            gld16(&dwls[pb][(tid>>3)*32 + (tid&7)*4],
                  dwp + (tid>>3)*K0 + c0 + (tid&7)*4);
        const float* src; int str, coff;
        if(CONCAT){
            if(c0 < 96)      { src = cost; str = NSP; coff = c0; }
            else if(c0 < 224){ src = prv;  str = 128; coff = c0-96; }
            else             { src = nxt;  str = 128; coff = c0-224; }
        } else { src = xin; str = CINR; coff = c0; }
        const float* sb = src + (size_t)b*HH*WW*str + coff;
        float* xp = &xs[pb][0];
#pragma unroll
        for(int it=0;it<7;it++){
            int e = it*256 + tid;
            if(e < 1620){                               // prefix mask only
                int hp = e/9, q = e - hp*9;
                int hy = y0-1 + hp/18, hx = x0-1 + hp%18;
                bool ok = (q < 8) && hy>=0 && hy<HH && hx>=0 && hx<WW;
                const float* gp = ok ? (sb + ((size_t)hy*WW + hx)*str + q*4)
                                     : zb;
                gld16(xp + hp*36 + q*4, gp);
            }
        }
    };

    // depthwise work identity: 4 consecutive px (same row), 4 channels
    const int c4  = tid & 7;           // channel quartet 0..7
    const int pxg = tid >> 3;          // pixel group 0..31
    const int dpy = pxg >> 2;          // tile row 0..7
    const int dxb = (pxg & 3) * 4;     // tile col base 0,4,8,12

    stage(0, 0);
    int pb = 0;
    for(int c0=0;c0<K0;c0+=32){
        __syncthreads();   // drains this chunk's DMA (issued last iteration)
        // ---- B fragments for this chunk (issued before prefetch DMA) ----
        const int k8 = (c0>>3) + quad;
        short8 Bh[TN], Bl[TN];
#pragma unroll
        for(int nt=0;nt<TN;nt++){
            int n = wn*(NP/2) + nt*16 + l15;
            size_t off = ((size_t)k8*NP + n)*8;
            Bh[nt] = *(const short8*)(wh + off);
            Bl[nt] = *(const short8*)(wl + off);
        }
        // ---- prefetch next chunk into the other buffer ----
        if(c0+32 < K0) stage(c0+32, pb^1);
        // ---- depthwise 3x3: 4 px x 4 ch per thread, sliding 6-col window ----
        const float* xp = &xs[pb][0];
        const float* dwc = &dwls[pb][0];
        {
            float4 o[4];
#pragma unroll
            for(int dx=0;dx<4;dx++) o[dx] = make_float4(0.f,0.f,0.f,0.f);
#pragma unroll
            for(int kh=0;kh<3;kh++){
                float4 xw[6];
#pragma unroll
                for(int t=0;t<6;t++)
                    xw[t] = *(const float4*)&xp[((dpy+kh)*18 + dxb + t)*36 + c4*4];
#pragma unroll
                for(int kw=0;kw<3;kw++){
                    float4 w4 = *(const float4*)&dwc[(kh*3+kw)*32 + c4*4];
#pragma unroll
                    for(int dx=0;dx<4;dx++){
                        float4 xv = xw[kw+dx];
                        o[dx].x = fmaf(xv.x,w4.x,o[dx].x);
                        o[dx].y = fmaf(xv.y,w4.y,o[dx].y);
                        o[dx].z = fmaf(xv.z,w4.z,o[dx].z);
                        o[dx].w = fmaf(xv.w,w4.w,o[dx].w);
                    }
                }
            }
            const int wbase = (c4>>1)*DSLAB + (pxg*4)*8 + (c4&1)*4;
#pragma unroll
            for(int dx=0;dx<4;dx++){
                float4 s = o[dx];
                short h0=bf16h(s.x), h1=bf16h(s.y), h2=bf16h(s.z), h3=bf16h(s.w);
                short l0=bf16h(s.x-bf16f(h0)), l1=bf16h(s.y-bf16f(h1));
                short l2=bf16h(s.z-bf16f(h2)), l3=bf16h(s.w-bf16f(h3));
                *(short4*)&dshh[wbase + dx*8] = make_short4(h0,h1,h2,h3);
                *(short4*)&dshl[wbase + dx*8] = make_short4(l0,l1,l2,l3);
            }
        }
        lds_barrier();     // orders dsh writes/reads; DMA keeps flying
        // ---- MFMA: A from LDS, B from registers ----
#pragma unroll
        for(int i=0;i<4;i++){
            int ab = quad*DSLAB + (wm*64 + i*16 + l15)*8;
            short8 Ah = *(const short8*)&dshh[ab];
            short8 Al = *(const short8*)&dshl[ab];
#pragma unroll
            for(int nt=0;nt<TN;nt++){
                f32x4 c = acc[i][nt];
                c = __builtin_amdgcn_mfma_f32_16x16x32_bf16(Ah,Bh[nt],c,0,0,0);
                c = __builtin_amdgcn_mfma_f32_16x16x32_bf16(Al,Bh[nt],c,0,0,0);
                c = __builtin_amdgcn_mfma_f32_16x16x32_bf16(Ah,Bl[nt],c,0,0,0);
                acc[i][nt] = c;
            }
        }
        lds_barrier();     // dsh reads done before next chunk's dw writes
        pb ^= 1;
    }
    // ---- epilogue: bias + mish + store ----
#pragma unroll
    for(int i=0;i<4;i++){
        int pxb = wm*64 + i*16 + quad*4;
#pragma unroll
        for(int nt=0;nt<TN;nt++){
            int cout = wn*(NP/2) + nt*16 + l15;
            if(cout < COUT){
                float bv = BIAS ? bias[cout] : 0.f;
#pragma unroll
                for(int r=0;r<4;r++){
                    int p = pxb + r;
                    int y = y0 + (p>>4), x = x0 + (p&15);
                    float v = acc[i][nt][r] + bv;
                    if(ACT) v = mish_f(v);
                    out[(((size_t)b*HH + y)*WW + x)*COUT + cout] = v;
                }
            }
        }
    }
}

// ---------------------------------------------------------------------------
extern "C" void kernel_launch(void* const* d_in, const int* in_sizes, int n_in,
                              void* d_out, int out_size, void* d_ws, size_t ws_size,
                              hipStream_t stream)
{
    (void)in_sizes; (void)n_in; (void)out_size;
    const float* prv = (const float*)d_in[0];
    const float* nxt = (const float*)d_in[1];
    const float* dws[6] = {(const float*)d_in[2],(const float*)d_in[5],(const float*)d_in[8],
                           (const float*)d_in[11],(const float*)d_in[14],(const float*)d_in[17]};
    const float* pws[6] = {(const float*)d_in[3],(const float*)d_in[6],(const float*)d_in[9],
                           (const float*)d_in[12],(const float*)d_in[15],(const float*)d_in[18]};
    const float* b0  = (const float*)d_in[4];
    const float* b1  = (const float*)d_in[7];
    const float* b2  = (const float*)d_in[10];
    const float* b3  = (const float*)d_in[13];
    const float* b4  = (const float*)d_in[16];

    // ---- weight slabs: pw hi/lo bf16 + dw fp32 [9][K0] + zero scratch ----
    const int   Ks[6]   = {337,128,128, 96, 64, 32};
    const int   K0s[6]  = {352,128,128, 96, 64, 32};
    const int   Ns[6]   = {128,128, 96, 64, 32,  2};
    const int   NPs[6]  = {128,128, 96, 64, 32, 32};
    const int   rmp[6]  = {  1,  0,  0,  0,  0,  0};
    size_t offs[6]; size_t E = 0;
    for(int i=0;i<6;i++){ offs[i] = E; E += (size_t)K0s[i]*NPs[i]; }
    size_t dwoffs[6]; size_t Edw = 0;
    for(int i=0;i<6;i++){ dwoffs[i] = Edw; Edw += (size_t)9*K0s[i]; }

    short* Whs = (short*)d_ws;
    short* Wls = Whs + E;
    float* Dwp = (float*)((char*)d_ws + ((E*2*sizeof(short) + 255) & ~(size_t)255));
    float* Zb  = Dwp + Edw;                    // 64-float zero scratch
    size_t wbytes = (((char*)(Zb + 64) - (char*)d_ws) + 255) & ~(size_t)255;

    zero_k<<<1,64,0,stream>>>(Zb, 64);
    for(int i=0;i<6;i++){
        int total = K0s[i]*NPs[i];
        prep_pw<<<(total+255)/256,256,0,stream>>>(pws[i], Whs+offs[i], Wls+offs[i],
                                                  Ks[i], Ns[i], NPs[i], total, rmp[i]);
        int tdw = 9*K0s[i];
        prep_dw<<<(tdw+255)/256,256,0,stream>>>(dws[i], Dwp+dwoffs[i],
                                                Ks[i], K0s[i], rmp[i], tdw);
    }

    // ---- activation buffers, batch-chunked ----
    const size_t per_batch_floats = (size_t)HWPIX * (NSP + 128 + 128);
    size_t avail = (ws_size > wbytes) ? (ws_size - wbytes) : 0;
    int NB = (int)(avail / (per_batch_floats * sizeof(float)));
    if(NB > BATCH) NB = BATCH;
    if(NB < 1)     NB = 1;
    while(BATCH % NB) NB--;

    float* fbase = (float*)((char*)d_ws + wbytes);
    float* costb = fbase;
    float* bufA  = costb + (size_t)NB*HWPIX*NSP;
    float* bufB  = bufA  + (size_t)NB*HWPIX*128;

    for(int bb=0; bb<BATCH; bb+=NB){
        const float* prv_o = prv + (size_t)bb*HWPIX*CC;
        const float* nxt_o = nxt + (size_t)bb*HWPIX*CC;
        float*       out_o = (float*)d_out + (size_t)bb*HWPIX*2;
        dim3 gc(WW/16, HH/16, NB);
        dim3 gs(WW/16, HH/8,  NB);

        cost_mfma<<<gc,512,0,stream>>>(prv_o, nxt_o, costb);
        sep_mfma<337,352,128,128,true ,true ,true ><<<gs,256,0,stream>>>(nullptr, costb, prv_o, nxt_o, Dwp+dwoffs[0], Whs+offs[0], Wls+offs[0], b0, Zb, bufA);
        sep_mfma<128,128,128,128,true ,true ,false><<<gs,256,0,stream>>>(bufA, nullptr,nullptr,nullptr, Dwp+dwoffs[1], Whs+offs[1], Wls+offs[1], b1, Zb, bufB);
        sep_mfma<128,128, 96, 96,true ,true ,false><<<gs,256,0,stream>>>(bufB, nullptr,nullptr,nullptr, Dwp+dwoffs[2], Whs+offs[2], Wls+offs[2], b2, Zb, bufA);
        sep_mfma< 96, 96, 64, 64,true ,true ,false><<<gs,256,0,stream>>>(bufA, nullptr,nullptr,nullptr, Dwp+dwoffs[3], Whs+offs[3], Wls+offs[3], b3, Zb, bufB);
        sep_mfma< 64, 64, 32, 32,true ,true ,false><<<gs,256,0,stream>>>(bufB, nullptr,nullptr,nullptr, Dwp+dwoffs[4], Whs+offs[4], Wls+offs[4], b4, Zb, bufA);
        sep_mfma< 32, 32,  2, 32,false,false,false><<<gs,256,0,stream>>>(bufA, nullptr,nullptr,nullptr, Dwp+dwoffs[5], Whs+offs[5], Wls+offs[5], nullptr, Zb, out_o);
    }
}

// Round 7
// 574.505 us; speedup vs baseline: 1.3447x; 1.3244x over previous
//
#include <hip/hip_runtime.h>
#include <math.h>

// Problem constants (B=8, H=W=128, C=128, R=4 -> 81 cost channels)
#define BATCH 8
#define HH 128
#define WW 128
#define CC 128
#define RR 4
#define DDIM 9
#define NS 81
#define NSP 96          // cost channels padded to 96 (zero-filled 81..95)
#define HWPIX (HH*WW)
#define DSLAB 1032      // dsh slab stride in shorts (1024 + 8: kills 4-way write conflicts)

typedef short  short8  __attribute__((ext_vector_type(8)));
typedef float  f32x4   __attribute__((ext_vector_type(4)));

__device__ __forceinline__ short bf16h(float f){
    unsigned u = __float_as_uint(f);
    u += 0x7fffu + ((u >> 16) & 1u);
    return (short)(u >> 16);
}
__device__ __forceinline__ float bf16f(short s){
    return __uint_as_float(((unsigned)(unsigned short)s) << 16);
}
__device__ __forceinline__ float mish_f(float x){
    float xc = fminf(x, 30.f);
    float t = expf(xc);
    float u = t*t + 2.f*t;
    return x * (u / (u + 2.f));
}

// async global->LDS DMA, 16 B/lane.  LDS dest = first-active-lane base +
// lane*16 => prefix-only masking, OOB lanes read a zero-scratch global addr.
__device__ __forceinline__ void gld16(float* lds, const float* g){
    __builtin_amdgcn_global_load_lds(
        (const __attribute__((address_space(1))) unsigned int*)g,
        (__attribute__((address_space(3))) unsigned int*)lds, 16, 0, 0);
}

// LDS-only barrier: orders ds_write/ds_read without draining vmcnt.
__device__ __forceinline__ void lds_barrier(){
    __asm volatile("s_waitcnt lgkmcnt(0)\n\ts_barrier" ::: "memory");
}

__global__ void zero_k(float* p, int n){
    int i = blockIdx.x*256 + threadIdx.x;
    if(i < n) p[i] = 0.f;
}

// convert 8 fp32 -> hi/lo bf16 short8 pair
__device__ __forceinline__ void cvt8(const float4& a, const float4& b,
                                     short8& h, short8& l){
    float v0=a.x,v1=a.y,v2=a.z,v3=a.w,v4=b.x,v5=b.y,v6=b.z,v7=b.w;
    short h0=bf16h(v0),h1=bf16h(v1),h2=bf16h(v2),h3=bf16h(v3);
    short h4=bf16h(v4),h5=bf16h(v5),h6=bf16h(v6),h7=bf16h(v7);
    h[0]=h0;h[1]=h1;h[2]=h2;h[3]=h3;h[4]=h4;h[5]=h5;h[6]=h6;h[7]=h7;
    l[0]=bf16h(v0-bf16f(h0)); l[1]=bf16h(v1-bf16f(h1));
    l[2]=bf16h(v2-bf16f(h2)); l[3]=bf16h(v3-bf16f(h3));
    l[4]=bf16h(v4-bf16f(h4)); l[5]=bf16h(v5-bf16f(h5));
    l[6]=bf16h(v6-bf16f(h6)); l[7]=bf16h(v7-bf16f(h7));
}

// ---------------------------------------------------------------------------
// Cost volume as banded GEMM on matrix cores.
// cost(tx,i,j) at row y = band of A.B^T: A = prv[y][x0..x0+15][:] (16x128),
// B = nxt[y+i-4][x0-4..x0+19][:] (24x128).  Two 16x16 n-tiles cover the
// 9-diagonal band.  Split-bf16 4-term MFMA for ~fp32 accuracy.
// Block 16x16 px, 512 thr / 8 waves; wave = 2 y-rows x 9 i.  nxt staged
// per-32ch-chunk in LDS as frag-ready hi/lo short slabs.
// __launch_bounds__(512,2): 1 block/CU, 256-VGPR budget.  r5/r6 used (512,4)
// which capped VGPRs at 64 -> the 144-reg accumulator array spilled to
// scratch, generating ~1 GB/dispatch of HBM traffic (WRITE_SIZE 624 MB,
// VGPR_Count=64 in the profile).  The accumulators must live in registers.
// Epilogue: band scattered into LDS staging (smem reuse), pad channels
// zeroed in LDS, streamed out as contiguous float4 stores.
// ---------------------------------------------------------------------------
__global__ __launch_bounds__(512,2) void cost_mfma(
    const float* __restrict__ prv, const float* __restrict__ nxt,
    float* __restrict__ cost)
{
    __shared__ char smem[73728];
    short* bhs = (short*)smem;              // [r][ch-octet][col][8ch] hi (36864 B)
    short* bls = (short*)(smem + 36864);    // lo (36864 B)
    const int tid  = threadIdx.x;
    const int lane = tid & 63, wv = tid >> 6;      // wv 0..7
    const int l15  = lane & 15, quad = lane >> 4;
    const int x0 = blockIdx.x*16, y0 = blockIdx.y*16, b = blockIdx.z;
    const int Y = wv*2;                             // wave's 2 tile rows

    const float* prvb = prv + (((size_t)b*HH + y0)*WW + x0)*CC;
    const float* nxb  = nxt + (size_t)b*HH*WW*CC;

    f32x4 acc[2][9][2];
#pragma unroll
    for(int yy=0;yy<2;yy++)
#pragma unroll
        for(int i=0;i<9;i++){
            acc[yy][i][0] = (f32x4){0.f,0.f,0.f,0.f};
            acc[yy][i][1] = (f32x4){0.f,0.f,0.f,0.f};
        }

    float4 sreg[9];
    auto sload = [&](int kc){
#pragma unroll
        for(int s=0;s<9;s++){
            int e = s*512 + tid;                    // 0..4607, bijective
            int px = e >> 3, q = e & 7;             // px 0..575, ch-quartet
            int r = px/24, c = px - r*24;
            int hy = y0 - 4 + r, hx = x0 - 4 + c;
            bool ok = hy>=0 && hy<HH && hx>=0 && hx<WW;
            sreg[s] = ok ? *(const float4*)(nxb + ((size_t)hy*WW + hx)*CC + kc*32 + q*4)
                         : make_float4(0.f,0.f,0.f,0.f);
        }
    };
    sload(0);

    for(int kc=0; kc<4; kc++){
        __syncthreads();                 // readers of previous chunk done
        // ---- write staged regs -> frag-ready hi/lo slabs ----
#pragma unroll
        for(int s=0;s<9;s++){
            int e = s*512 + tid;
            int px = e >> 3, q = e & 7;
            int r = px/24, c = px - r*24;
            int base = ((r*4 + (q>>1))*24 + c)*8 + (q&1)*4;
            float4 v = sreg[s];
            short h0=bf16h(v.x), h1=bf16h(v.y), h2=bf16h(v.z), h3=bf16h(v.w);
            *(short4*)&bhs[base] = make_short4(h0,h1,h2,h3);
            *(short4*)&bls[base] = make_short4(bf16h(v.x-bf16f(h0)),
                                               bf16h(v.y-bf16f(h1)),
                                               bf16h(v.z-bf16f(h2)),
                                               bf16h(v.w-bf16f(h3)));
        }
        if(kc < 3) sload(kc+1);          // prefetch next chunk (T14)
        // ---- A-frags: prv rows, direct global + convert ----
        short8 Ah[2], Al[2];
#pragma unroll
        for(int yy=0; yy<2; yy++){
            const float* ap = prvb + ((size_t)(Y+yy)*WW + l15)*CC + kc*32 + quad*8;
            float4 f0v = *(const float4*)ap;
            float4 f1v = *(const float4*)(ap+4);
            cvt8(f0v, f1v, Ah[yy], Al[yy]);
        }
        lds_barrier();                   // slab writes visible
        // ---- banded MFMA: rows r = Y..Y+9, jobs (yy, i=rr-yy) ----
#pragma unroll
        for(int rr=0; rr<10; rr++){
            int r  = Y + rr;
            int rb = (r*4 + quad)*24*8;
            short8 Bh0 = *(const short8*)&bhs[rb + l15*8];
            short8 Bl0 = *(const short8*)&bls[rb + l15*8];
            short8 Bh1 = *(const short8*)&bhs[rb + (8+l15)*8];
            short8 Bl1 = *(const short8*)&bls[rb + (8+l15)*8];
#pragma unroll
            for(int yy=0; yy<2; yy++){
                int i = rr - yy;
                if(i >= 0 && i <= 8){
                    f32x4 c0 = acc[yy][i][0];
                    c0 = __builtin_amdgcn_mfma_f32_16x16x32_bf16(Ah[yy],Bh0,c0,0,0,0);
                    c0 = __builtin_amdgcn_mfma_f32_16x16x32_bf16(Al[yy],Bh0,c0,0,0,0);
                    c0 = __builtin_amdgcn_mfma_f32_16x16x32_bf16(Ah[yy],Bl0,c0,0,0,0);
                    c0 = __builtin_amdgcn_mfma_f32_16x16x32_bf16(Al[yy],Bl0,c0,0,0,0);
                    acc[yy][i][0] = c0;
                    f32x4 c1 = acc[yy][i][1];
                    c1 = __builtin_amdgcn_mfma_f32_16x16x32_bf16(Ah[yy],Bh1,c1,0,0,0);
                    c1 = __builtin_amdgcn_mfma_f32_16x16x32_bf16(Al[yy],Bh1,c1,0,0,0);
                    c1 = __builtin_amdgcn_mfma_f32_16x16x32_bf16(Ah[yy],Bl1,c1,0,0,0);
                    c1 = __builtin_amdgcn_mfma_f32_16x16x32_bf16(Al[yy],Bl1,c1,0,0,0);
                    acc[yy][i][1] = c1;
                }
            }
        }
    }
    // ---- epilogue: scatter band -> LDS staging -> coalesced float4 stores.
    // D layout: row m = quad*4+reg, col n = l15.  nt0: j=n-m; nt1: j=8+n-m.
    // Partition by u<16 / u>=16: each (m, j) has exactly one writer, all 81
    // channels covered.  2 passes x 8 rows (49152 B staging <= 73728 B smem).
    const float sc = 1.f/128.f;
    float* obuf = (float*)smem;          // [128 px][96 ch]
    const int grp = wv >> 2;             // wave row-group == pass index
#pragma unroll
    for(int p=0; p<2; p++){
        lds_barrier();                   // prior smem readers done
        if(grp == p){                    // wave-uniform branch, no barrier inside
#pragma unroll
            for(int yy=0; yy<2; yy++){
                int rl = (Y + yy - p*8)*16;        // local px row base
#pragma unroll
                for(int i=0;i<9;i++){
#pragma unroll
                    for(int rg=0; rg<4; rg++){
                        int m  = quad*4 + rg;
                        int j0 = l15 - m;
                        if(j0 >= 0 && j0 <= 8)
                            obuf[(rl + m)*96 + i*9 + j0] = acc[yy][i][0][rg]*sc;
                        int j1 = 8 + l15 - m;
                        if(l15 >= 8 && j1 <= 8)
                            obuf[(rl + m)*96 + i*9 + j1] = acc[yy][i][1][rg]*sc;
                    }
                }
            }
        }
        // zero pad channels 81..95 (disjoint addresses from the scatter)
        for(int e = tid; e < 1920; e += 512){
            int px = e/15, c = e - px*15;
            obuf[px*96 + 81 + c] = 0.f;
        }
        lds_barrier();
        // rows y0+8p..+7: per row 16 px x 96 ch = 1536 floats contiguous
        float* gbase = cost + (((size_t)b*HH + y0 + p*8)*WW + x0)*NSP;
#pragma unroll
        for(int it=0; it<6; it++){
            int e = it*512 + tid;        // 0..3071 float4 slots
            int r = e/384, o = e - r*384;
            float4 v = *(const float4*)&obuf[r*1536 + o*4];
            *(float4*)&gbase[(size_t)r*WW*NSP + o*4] = v;
        }
    }
}

// ---------------------------------------------------------------------------
// Pointwise weight prep (hi/lo bf16 B-fragment slabs), remap for padded concat.
// ---------------------------------------------------------------------------
__global__ void prep_pw(const float* __restrict__ src, short* __restrict__ dh,
                        short* __restrict__ dl, int K, int N, int NP, int total,
                        int remap)
{
    int idx = blockIdx.x*256 + threadIdx.x;
    if(idx >= total) return;
    int j  = idx & 7;
    int n  = (idx>>3) % NP;
    int k8 = (idx>>3) / NP;
    int k  = k8*8 + j;
    if(remap) k = (k < 81) ? k : ((k < 96) ? -1 : k - 15);
    float v = (k>=0 && k<K && n<N) ? src[(size_t)k*N + n] : 0.f;
    short h = bf16h(v);
    dh[idx] = h;
    dl[idx] = bf16h(v - bf16f(h));
}

// Depthwise weight prep: [9][K0] slab, remapped/zero-padded.
__global__ void prep_dw(const float* __restrict__ src, float* __restrict__ dst,
                        int K, int K0, int remap, int total)
{
    int idx = blockIdx.x*256 + threadIdx.x;
    if(idx >= total) return;
    int k = idx / K0, c = idx - k*K0;
    int cr = c;
    if(remap) cr = (c < 81) ? c : ((c < 96) ? -1 : c - 15);
    dst[idx] = (cr>=0 && cr<K) ? src[k*K + cr] : 0.f;
}

// ---------------------------------------------------------------------------
// Fused depthwise-3x3 (fp32 VALU) + pointwise-1x1 (split-bf16 MFMA, fp32 acc).
// Tile 16x8 px, 4 waves 2(m)x2(n).  K-chunks of 32, double-buffered DMA
// staging; chunk k+1's DMA issued after chunk k's opening barrier; lgkm-only
// mid barrier keeps the prefetch in flight through the MFMA phase.
// Depthwise: one thread = 4 consecutive px x 4 ch (sliding 6-col window).
// dsh slab stride DSLAB=1032 shorts kills the 4-way write conflicts.
// ---------------------------------------------------------------------------
template<int CINR,int K0,int COUT,int NP,bool BIAS,bool ACT,bool CONCAT>
__global__ __launch_bounds__(256,2) void sep_mfma(
    const float* __restrict__ xin, const float* __restrict__ cost,
    const float* __restrict__ prv, const float* __restrict__ nxt,
    const float* __restrict__ dwp, const short* __restrict__ wh,
    const short* __restrict__ wl, const float* __restrict__ bias,
    const float* __restrict__ zb, float* __restrict__ out)
{
    constexpr int TN = NP/32;           // n-tiles per wave (16 couts each)
    __shared__ float xs[2][180*36];     // halo 10(y) x 18(x), stride 36
    __shared__ short dshh[4*DSLAB];     // [k8][px][j]  hi
    __shared__ short dshl[4*DSLAB];     // [k8][px][j]  lo
    __shared__ float dwls[2][9*32];

    const int tid = threadIdx.x;
    const int x0 = blockIdx.x*16, y0 = blockIdx.y*8, b = blockIdx.z;
    const int lane = tid & 63;
    const int wv   = tid >> 6;
    const int wm   = wv >> 1, wn = wv & 1;
    const int l15  = lane & 15, quad = lane >> 4;

    f32x4 acc[4][TN];
#pragma unroll
    for(int i=0;i<4;i++)
#pragma unroll
        for(int nt=0;nt<TN;nt++) acc[i][nt] = (f32x4){0.f,0.f,0.f,0.f};

    auto stage = [&](int c0, int pb){
        if(tid < 72)
            gld16(&dwls[pb][(tid>>3)*32 + (tid&7)*4],
                  dwp + (tid>>3)*K0 + c0 + (tid&7)*4);
        const float* src; int str, coff;
        if(CONCAT){
            if(c0 < 96)      { src = cost; str = NSP; coff = c0; }
            else if(c0 < 224){ src = prv;  str = 128; coff = c0-96; }
            else             { src = nxt;  str = 128; coff = c0-224; }
        } else { src = xin; str = CINR; coff = c0; }
        const float* sb = src + (size_t)b*HH*WW*str + coff;
        float* xp = &xs[pb][0];
#pragma unroll
        for(int it=0;it<7;it++){
            int e = it*256 + tid;
            if(e < 1620){                               // prefix mask only
                int hp = e/9, q = e - hp*9;
                int hy = y0-1 + hp/18, hx = x0-1 + hp%18;
                bool ok = (q < 8) && hy>=0 && hy<HH && hx>=0 && hx<WW;
                const float* gp = ok ? (sb + ((size_t)hy*WW + hx)*str + q*4)
                                     : zb;
                gld16(xp + hp*36 + q*4, gp);
            }
        }
    };

    // depthwise work identity: 4 consecutive px (same row), 4 channels
    const int c4  = tid & 7;           // channel quartet 0..7
    const int pxg = tid >> 3;          // pixel group 0..31
    const int dpy = pxg >> 2;          // tile row 0..7
    const int dxb = (pxg & 3) * 4;     // tile col base 0,4,8,12

    stage(0, 0);
    int pb = 0;
    for(int c0=0;c0<K0;c0+=32){
        __syncthreads();   // drains this chunk's DMA (issued last iteration)
        // ---- B fragments for this chunk (issued before prefetch DMA) ----
        const int k8 = (c0>>3) + quad;
        short8 Bh[TN], Bl[TN];
#pragma unroll
        for(int nt=0;nt<TN;nt++){
            int n = wn*(NP/2) + nt*16 + l15;
            size_t off = ((size_t)k8*NP + n)*8;
            Bh[nt] = *(const short8*)(wh + off);
            Bl[nt] = *(const short8*)(wl + off);
        }
        // ---- prefetch next chunk into the other buffer ----
        if(c0+32 < K0) stage(c0+32, pb^1);
        // ---- depthwise 3x3: 4 px x 4 ch per thread, sliding 6-col window ----
        const float* xp = &xs[pb][0];
        const float* dwc = &dwls[pb][0];
        {
            float4 o[4];
#pragma unroll
            for(int dx=0;dx<4;dx++) o[dx] = make_float4(0.f,0.f,0.f,0.f);
#pragma unroll
            for(int kh=0;kh<3;kh++){
                float4 xw[6];
#pragma unroll
                for(int t=0;t<6;t++)
                    xw[t] = *(const float4*)&xp[((dpy+kh)*18 + dxb + t)*36 + c4*4];
#pragma unroll
                for(int kw=0;kw<3;kw++){
                    float4 w4 = *(const float4*)&dwc[(kh*3+kw)*32 + c4*4];
#pragma unroll
                    for(int dx=0;dx<4;dx++){
                        float4 xv = xw[kw+dx];
                        o[dx].x = fmaf(xv.x,w4.x,o[dx].x);
                        o[dx].y = fmaf(xv.y,w4.y,o[dx].y);
                        o[dx].z = fmaf(xv.z,w4.z,o[dx].z);
                        o[dx].w = fmaf(xv.w,w4.w,o[dx].w);
                    }
                }
            }
            const int wbase = (c4>>1)*DSLAB + (pxg*4)*8 + (c4&1)*4;
#pragma unroll
            for(int dx=0;dx<4;dx++){
                float4 s = o[dx];
                short h0=bf16h(s.x), h1=bf16h(s.y), h2=bf16h(s.z), h3=bf16h(s.w);
                short l0=bf16h(s.x-bf16f(h0)), l1=bf16h(s.y-bf16f(h1));
                short l2=bf16h(s.z-bf16f(h2)), l3=bf16h(s.w-bf16f(h3));
                *(short4*)&dshh[wbase + dx*8] = make_short4(h0,h1,h2,h3);
                *(short4*)&dshl[wbase + dx*8] = make_short4(l0,l1,l2,l3);
            }
        }
        lds_barrier();     // orders dsh writes/reads; DMA keeps flying
        // ---- MFMA: A from LDS, B from registers ----
#pragma unroll
        for(int i=0;i<4;i++){
            int ab = quad*DSLAB + (wm*64 + i*16 + l15)*8;
            short8 Ah = *(const short8*)&dshh[ab];
            short8 Al = *(const short8*)&dshl[ab];
#pragma unroll
            for(int nt=0;nt<TN;nt++){
                f32x4 c = acc[i][nt];
                c = __builtin_amdgcn_mfma_f32_16x16x32_bf16(Ah,Bh[nt],c,0,0,0);
                c = __builtin_amdgcn_mfma_f32_16x16x32_bf16(Al,Bh[nt],c,0,0,0);
                c = __builtin_amdgcn_mfma_f32_16x16x32_bf16(Ah,Bl[nt],c,0,0,0);
                acc[i][nt] = c;
            }
        }
        lds_barrier();     // dsh reads done before next chunk's dw writes
        pb ^= 1;
    }
    // ---- epilogue: bias + mish + store ----
#pragma unroll
    for(int i=0;i<4;i++){
        int pxb = wm*64 + i*16 + quad*4;
#pragma unroll
        for(int nt=0;nt<TN;nt++){
            int cout = wn*(NP/2) + nt*16 + l15;
            if(cout < COUT){
                float bv = BIAS ? bias[cout] : 0.f;
#pragma unroll
                for(int r=0;r<4;r++){
                    int p = pxb + r;
                    int y = y0 + (p>>4), x = x0 + (p&15);
                    float v = acc[i][nt][r] + bv;
                    if(ACT) v = mish_f(v);
                    out[(((size_t)b*HH + y)*WW + x)*COUT + cout] = v;
                }
            }
        }
    }
}

// ---------------------------------------------------------------------------
extern "C" void kernel_launch(void* const* d_in, const int* in_sizes, int n_in,
                              void* d_out, int out_size, void* d_ws, size_t ws_size,
                              hipStream_t stream)
{
    (void)in_sizes; (void)n_in; (void)out_size;
    const float* prv = (const float*)d_in[0];
    const float* nxt = (const float*)d_in[1];
    const float* dws[6] = {(const float*)d_in[2],(const float*)d_in[5],(const float*)d_in[8],
                           (const float*)d_in[11],(const float*)d_in[14],(const float*)d_in[17]};
    const float* pws[6] = {(const float*)d_in[3],(const float*)d_in[6],(const float*)d_in[9],
                           (const float*)d_in[12],(const float*)d_in[15],(const float*)d_in[18]};
    const float* b0  = (const float*)d_in[4];
    const float* b1  = (const float*)d_in[7];
    const float* b2  = (const float*)d_in[10];
    const float* b3  = (const float*)d_in[13];
    const float* b4  = (const float*)d_in[16];

    // ---- weight slabs: pw hi/lo bf16 + dw fp32 [9][K0] + zero scratch ----
    const int   Ks[6]   = {337,128,128, 96, 64, 32};
    const int   K0s[6]  = {352,128,128, 96, 64, 32};
    const int   Ns[6]   = {128,128, 96, 64, 32,  2};
    const int   NPs[6]  = {128,128, 96, 64, 32, 32};
    const int   rmp[6]  = {  1,  0,  0,  0,  0,  0};
    size_t offs[6]; size_t E = 0;
    for(int i=0;i<6;i++){ offs[i] = E; E += (size_t)K0s[i]*NPs[i]; }
    size_t dwoffs[6]; size_t Edw = 0;
    for(int i=0;i<6;i++){ dwoffs[i] = Edw; Edw += (size_t)9*K0s[i]; }

    short* Whs = (short*)d_ws;
    short* Wls = Whs + E;
    float* Dwp = (float*)((char*)d_ws + ((E*2*sizeof(short) + 255) & ~(size_t)255));
    float* Zb  = Dwp + Edw;                    // 64-float zero scratch
    size_t wbytes = (((char*)(Zb + 64) - (char*)d_ws) + 255) & ~(size_t)255;

    zero_k<<<1,64,0,stream>>>(Zb, 64);
    for(int i=0;i<6;i++){
        int total = K0s[i]*NPs[i];
        prep_pw<<<(total+255)/256,256,0,stream>>>(pws[i], Whs+offs[i], Wls+offs[i],
                                                  Ks[i], Ns[i], NPs[i], total, rmp[i]);
        int tdw = 9*K0s[i];
        prep_dw<<<(tdw+255)/256,256,0,stream>>>(dws[i], Dwp+dwoffs[i],
                                                Ks[i], K0s[i], rmp[i], tdw);
    }

    // ---- activation buffers, batch-chunked ----
    const size_t per_batch_floats = (size_t)HWPIX * (NSP + 128 + 128);
    size_t avail = (ws_size > wbytes) ? (ws_size - wbytes) : 0;
    int NB = (int)(avail / (per_batch_floats * sizeof(float)));
    if(NB > BATCH) NB = BATCH;
    if(NB < 1)     NB = 1;
    while(BATCH % NB) NB--;

    float* fbase = (float*)((char*)d_ws + wbytes);
    float* costb = fbase;
    float* bufA  = costb + (size_t)NB*HWPIX*NSP;
    float* bufB  = bufA  + (size_t)NB*HWPIX*128;

    for(int bb=0; bb<BATCH; bb+=NB){
        const float* prv_o = prv + (size_t)bb*HWPIX*CC;
        const float* nxt_o = nxt + (size_t)bb*HWPIX*CC;
        float*       out_o = (float*)d_out + (size_t)bb*HWPIX*2;
        dim3 gc(WW/16, HH/16, NB);
        dim3 gs(WW/16, HH/8,  NB);

        cost_mfma<<<gc,512,0,stream>>>(prv_o, nxt_o, costb);
        sep_mfma<337,352,128,128,true ,true ,true ><<<gs,256,0,stream>>>(nullptr, costb, prv_o, nxt_o, Dwp+dwoffs[0], Whs+offs[0], Wls+offs[0], b0, Zb, bufA);
        sep_mfma<128,128,128,128,true ,true ,false><<<gs,256,0,stream>>>(bufA, nullptr,nullptr,nullptr, Dwp+dwoffs[1], Whs+offs[1], Wls+offs[1], b1, Zb, bufB);
        sep_mfma<128,128, 96, 96,true ,true ,false><<<gs,256,0,stream>>>(bufB, nullptr,nullptr,nullptr, Dwp+dwoffs[2], Whs+offs[2], Wls+offs[2], b2, Zb, bufA);
        sep_mfma< 96, 96, 64, 64,true ,true ,false><<<gs,256,0,stream>>>(bufA, nullptr,nullptr,nullptr, Dwp+dwoffs[3], Whs+offs[3], Wls+offs[3], b3, Zb, bufB);
        sep_mfma< 64, 64, 32, 32,true ,true ,false><<<gs,256,0,stream>>>(bufB, nullptr,nullptr,nullptr, Dwp+dwoffs[4], Whs+offs[4], Wls+offs[4], b4, Zb, bufA);
        sep_mfma< 32, 32,  2, 32,false,false,false><<<gs,256,0,stream>>>(bufA, nullptr,nullptr,nullptr, Dwp+dwoffs[5], Whs+offs[5], Wls+offs[5], nullptr, Zb, out_o);
    }
}